// Round 1
// baseline (502.330 us; speedup 1.0000x reference)
//
#include <hip/hip_runtime.h>
#include <cstdint>
#include <cstddef>

#define N 8192
#define D 128
#define KNN 20
#define NC 10
#define TS 64
#define CAP 2048
constexpr float EPS = 1e-10f;

// ---------------- K1: squared norms ----------------
__global__ void k_sqnorm(const float* __restrict__ X, float* __restrict__ sq) {
    int row = blockIdx.x;
    int lane = threadIdx.x;                      // 64 lanes
    const float2* X2 = (const float2*)(X + (size_t)row * D);
    float2 a = X2[lane];
    float s = a.x * a.x + a.y * a.y;
    #pragma unroll
    for (int off = 32; off; off >>= 1) s += __shfl_down(s, off, 64);
    if (lane == 0) sq[row] = s;
}

// ---------------- K2: distance tile GEMM (d2 = sqi + sqj - 2*x_i.x_j, clamped >= 0) ----
// LDS row layout: 16 logical 16B chunks + 7 pad chunks (stride 23 chunks = 92 floats),
// additive swizzle chunk' = chunk + ((r + (r>>3)) & 7)  -> conflict-free reads, linear-in-k addr.
__global__ __launch_bounds__(256) void k_dist(const float* __restrict__ X,
                                              const float* __restrict__ sqn,
                                              float* __restrict__ d2, int R0) {
    __shared__ float As[TS * 92];
    __shared__ float Bs[TS * 92];
    int t  = threadIdx.x;
    int tx = t & 15, ty = t >> 4;
    int rowTile = R0 + blockIdx.y * TS;          // global row base (band rows)
    int colTile = blockIdx.x * TS;               // global col base
    const float4* X4 = (const float4*)X;

    float acc[4][4];
    #pragma unroll
    for (int i = 0; i < 4; ++i)
        #pragma unroll
        for (int j = 0; j < 4; ++j) acc[i][j] = 0.f;

    int aoff[4], boff[4];
    #pragma unroll
    for (int q = 0; q < 4; ++q) {
        int r = 4 * ty + q; aoff[q] = r * 92 + (((r + (r >> 3)) & 7) << 2);
        int c = 4 * tx + q; boff[q] = c * 92 + (((c + (c >> 3)) & 7) << 2);
    }

    #pragma unroll
    for (int s = 0; s < 2; ++s) {                // two K-chunks of 64
        __syncthreads();
        #pragma unroll
        for (int p = 0; p < 4; ++p) {            // 1024 float4 per array / 256 thr
            int u  = t + 256 * p;
            int r  = u >> 4;                     // 0..63
            int k4 = u & 15;                     // 16B chunk within K-chunk
            int sw = (k4 + ((r + (r >> 3)) & 7)) << 2;
            float4 ga = X4[(size_t)(rowTile + r) * 32 + s * 16 + k4];
            *(float4*)&As[r * 92 + sw] = ga;
            float4 gb = X4[(size_t)(colTile + r) * 32 + s * 16 + k4];
            *(float4*)&Bs[r * 92 + sw] = gb;
        }
        __syncthreads();
        #pragma unroll
        for (int k4 = 0; k4 < 16; ++k4) {
            float4 a4[4], b4[4];
            #pragma unroll
            for (int q = 0; q < 4; ++q) a4[q] = *(const float4*)&As[aoff[q] + (k4 << 2)];
            #pragma unroll
            for (int q = 0; q < 4; ++q) b4[q] = *(const float4*)&Bs[boff[q] + (k4 << 2)];
            #pragma unroll
            for (int i = 0; i < 4; ++i)
                #pragma unroll
                for (int j = 0; j < 4; ++j) {
                    acc[i][j] = fmaf(a4[i].x, b4[j].x, acc[i][j]);
                    acc[i][j] = fmaf(a4[i].y, b4[j].y, acc[i][j]);
                    acc[i][j] = fmaf(a4[i].z, b4[j].z, acc[i][j]);
                    acc[i][j] = fmaf(a4[i].w, b4[j].w, acc[i][j]);
                }
        }
    }

    int lr0 = blockIdx.y * TS + 4 * ty;          // band-local row
    int gc0 = colTile + 4 * tx;                  // global col
    float sqa[4], sqb[4];
    #pragma unroll
    for (int q = 0; q < 4; ++q) { sqa[q] = sqn[R0 + lr0 + q]; sqb[q] = sqn[gc0 + q]; }
    #pragma unroll
    for (int i = 0; i < 4; ++i) {
        float4 o;
        o.x = fmaxf(sqa[i] + sqb[0] - 2.f * acc[i][0], 0.f);
        o.y = fmaxf(sqa[i] + sqb[1] - 2.f * acc[i][1], 0.f);
        o.z = fmaxf(sqa[i] + sqb[2] - 2.f * acc[i][2], 0.f);
        o.w = fmaxf(sqa[i] + sqb[3] - 2.f * acc[i][3], 0.f);
        *(float4*)&d2[(size_t)(lr0 + i) * N + gc0] = o;
    }
}

// ---------------- K3: exact 20-NN per row via threshold filter + u64 min rounds ----
__global__ __launch_bounds__(256) void k_select(const float* __restrict__ d2, int R0,
                                                int* __restrict__ knn_idx,
                                                float* __restrict__ density) {
    __shared__ float redf1[256], redf2[256];
    __shared__ int   redi[256];
    __shared__ unsigned long long list[CAP];
    __shared__ int lc;

    int lrow = blockIdx.x;
    int row  = R0 + lrow;
    int t    = threadIdx.x;
    const float4* rp = (const float4*)(d2 + (size_t)lrow * N);

    float v[32];
    #pragma unroll
    for (int p = 0; p < 8; ++p) {
        float4 g = rp[t + 256 * p];
        v[4 * p + 0] = g.x; v[4 * p + 1] = g.y; v[4 * p + 2] = g.z; v[4 * p + 3] = g.w;
    }

    float s1 = 0.f, s2 = 0.f;
    #pragma unroll
    for (int i = 0; i < 32; ++i) { s1 += v[i]; s2 = fmaf(v[i], v[i], s2); }
    redf1[t] = s1; redf2[t] = s2; __syncthreads();
    for (int sft = 128; sft; sft >>= 1) {
        if (t < sft) { redf1[t] += redf1[t + sft]; redf2[t] += redf2[t + sft]; }
        __syncthreads();
    }
    float mu    = redf1[0] * (1.f / N);
    float var   = redf2[0] * (1.f / N) - mu * mu;
    float sigma = sqrtf(fmaxf(var, 0.f)) + 1e-6f;
    __syncthreads();

    // find T with 20 <= count(v < T) <= CAP (first probe almost always accepted)
    float Tlo = 0.f, Thi = mu, T = mu - 2.2f * sigma;
    if (T <= 0.f) T = 0.5f * (Tlo + Thi);
    for (int it = 0; it < 32; ++it) {
        int c = 0;
        #pragma unroll
        for (int i = 0; i < 32; ++i) c += (v[i] < T) ? 1 : 0;
        redi[t] = c; __syncthreads();
        for (int sft = 128; sft; sft >>= 1) {
            if (t < sft) redi[t] += redi[t + sft];
            __syncthreads();
        }
        int n = redi[0]; __syncthreads();
        if (n >= KNN && n <= CAP) break;
        if (n < KNN) Tlo = T; else Thi = T;
        T = 0.5f * (Tlo + Thi);
    }

    if (t == 0) lc = 0;
    __syncthreads();
    #pragma unroll
    for (int i = 0; i < 32; ++i) {
        if (v[i] < T) {
            int pos = atomicAdd(&lc, 1);
            if (pos < CAP) {
                int j = 4 * (t + 256 * (i >> 2)) + (i & 3);
                unsigned long long key =
                    ((unsigned long long)__float_as_uint(v[i]) << 14) |
                    (unsigned long long)(j + 1);
                list[pos] = key;
            }
        }
    }
    __syncthreads();
    int n = min(lc, CAP);

    if (t < 64) {                                 // wave 0 does the final selection
        unsigned long long last = 0ull;
        float sumd = 0.f;
        for (int r = 0; r < KNN; ++r) {
            unsigned long long m = ~0ull;
            for (int sIdx = t; sIdx < n; sIdx += 64) {
                unsigned long long k = list[sIdx];
                if (k > last && k < m) m = k;
            }
            #pragma unroll
            for (int off = 32; off; off >>= 1) {
                unsigned long long o = __shfl_down(m, off, 64);
                if (o < m) m = o;
            }
            m = __shfl(m, 0, 64);
            last = m;
            if (t == 0) {
                int j = (int)(m & 16383ull) - 1;
                if (j < 0) j = 0; if (j >= N) j = N - 1;
                knn_idx[(size_t)row * KNN + r] = j;
                float dv = __uint_as_float((unsigned)(m >> 14));
                sumd += sqrtf(dv);
            }
        }
        if (t == 0) density[row] = 1.f / (sumd * (1.f / KNN) + EPS);
    }
}

// ---------------- K4: scatter knn + rnn (deduped) contributions ----------------
__global__ void k_scatter(const int* __restrict__ knn_idx, const float* __restrict__ density,
                          float* __restrict__ numer, float* __restrict__ cnt) {
    int p = blockIdx.x * 256 + threadIdx.x;
    if (p >= N * KNN) return;
    int i = p / KNN;
    int j = knn_idx[p];
    atomicAdd(&numer[i], density[j]);            // knn-side: j in knn(i)
    atomicAdd(&cnt[i], 1.f);
    bool found = false;                          // rnn-side: add i's density to j's row
    const int* kj = knn_idx + (size_t)j * KNN;   // unless i in knn(j) (already counted)
    #pragma unroll
    for (int m = 0; m < KNN; ++m) found |= (kj[m] == i);
    if (!found) {
        atomicAdd(&numer[j], density[i]);
        atomicAdd(&cnt[j], 1.f);
    }
}

// ---------------- K5: scores, flags, class preds ----------------
__global__ void k_final(const float* __restrict__ density, const float* __restrict__ numer,
                        const float* __restrict__ cnt, const float* __restrict__ logits,
                        float* __restrict__ out) {
    int i = blockIdx.x * 256 + threadIdx.x;
    if (i >= N) return;
    float c     = fmaxf(cnt[i], 1.f);
    float avg   = numer[i] / c;
    float score = -(density[i] / (avg + EPS));
    out[i] = score;
    bool flag = score < -0.5f;
    out[N + i] = flag ? 1.f : 0.f;
    const float* lg = logits + (size_t)i * NC;
    float best = lg[0]; int bi = 0;
    #pragma unroll
    for (int k = 1; k < NC; ++k) { float x = lg[k]; if (x > best) { best = x; bi = k; } }
    out[2 * N + i] = flag ? -1.f : (float)bi;
}

extern "C" void kernel_launch(void* const* d_in, const int* in_sizes, int n_in,
                              void* d_out, int out_size, void* d_ws, size_t ws_size,
                              hipStream_t stream) {
    const float* X      = (const float*)d_in[0];
    const float* logits = (const float*)d_in[1];
    float* out = (float*)d_out;

    char* ws = (char*)d_ws;
    float* sq      = (float*)ws; ws += (size_t)N * 4;
    float* density = (float*)ws; ws += (size_t)N * 4;
    float* numer   = (float*)ws; ws += (size_t)N * 4;
    float* cntb    = (float*)ws; ws += (size_t)N * 4;
    int*   knn     = (int*)ws;   ws += (size_t)N * KNN * 4;
    uintptr_t a = ((uintptr_t)ws + 255) & ~(uintptr_t)255;
    float* d2band = (float*)a;
    size_t used  = (size_t)((char*)d2band - (char*)d_ws);
    size_t avail = ws_size > used ? ws_size - used : 0;
    int band = (int)(avail / ((size_t)N * 4));
    band = (band / TS) * TS;
    if (band > N) band = N;
    if (band < TS) band = TS;                    // requires ws >= ~2.9 MB

    hipMemsetAsync(numer, 0, (size_t)N * 4, stream);
    hipMemsetAsync(cntb,  0, (size_t)N * 4, stream);

    k_sqnorm<<<N, 64, 0, stream>>>(X, sq);

    for (int R0 = 0; R0 < N; R0 += band) {
        int rows = min(band, N - R0);
        dim3 g(N / TS, rows / TS);
        k_dist<<<g, 256, 0, stream>>>(X, sq, d2band, R0);
        k_select<<<rows, 256, 0, stream>>>(d2band, R0, knn, density);
    }

    k_scatter<<<(N * KNN + 255) / 256, 256, 0, stream>>>(knn, density, numer, cntb);
    k_final<<<(N + 255) / 256, 256, 0, stream>>>(density, numer, cntb, logits, out);
}